// Round 6
// baseline (453.575 us; speedup 1.0000x reference)
//
#include <hip/hip_runtime.h>

#define S_LEN 2048
#define NHEAD 32
#define HD 80
#define DPAD 96
#define HIDDEN 2560
#define QKV_N 7680

typedef __attribute__((ext_vector_type(8))) short bf16x8;
typedef __attribute__((ext_vector_type(8))) unsigned short u16x8;
typedef __attribute__((ext_vector_type(4))) float f32x4;

__device__ __forceinline__ unsigned short f2bf(float f) {
  unsigned int u = __float_as_uint(f);
  u += 0x7fffu + ((u >> 16) & 1u);   // RNE
  return (unsigned short)(u >> 16);
}
__device__ __forceinline__ float bf2f(unsigned short h) {
  return __uint_as_float(((unsigned int)h) << 16);
}

__device__ __forceinline__ void gload16(const void* g, void* l) {
  __builtin_amdgcn_global_load_lds((const __attribute__((address_space(1))) void*)g,
                                   (__attribute__((address_space(3))) void*)l, 16, 0, 0);
}

// ---------------- fp32 -> bf16 elementwise ----------------
__global__ __launch_bounds__(256) void k_cvt(const float* __restrict__ in,
                                             unsigned short* __restrict__ out, int n4) {
  int i = blockIdx.x * 256 + threadIdx.x;
  if (i >= n4) return;
  float4 v = reinterpret_cast<const float4*>(in)[i];
  ushort4 o;
  o.x = f2bf(v.x); o.y = f2bf(v.y); o.z = f2bf(v.z); o.w = f2bf(v.w);
  reinterpret_cast<ushort4*>(out)[i] = o;
}

// ---------------- fp32 (R x C) -> bf16 transposed (C x R) ----------------
__global__ __launch_bounds__(256) void k_transpose_bf16(const float* __restrict__ in,
                                                        unsigned short* __restrict__ out,
                                                        int R, int C) {
  __shared__ float tile[64][65];
  int tc = blockIdx.x * 64, tr = blockIdx.y * 64;
  for (int i = threadIdx.x; i < 64 * 64; i += 256) {
    int r = i >> 6, c = i & 63;
    tile[r][c] = in[(size_t)(tr + r) * C + (tc + c)];
  }
  __syncthreads();
  for (int i = threadIdx.x; i < 64 * 64; i += 256) {
    int r = i >> 6, c = i & 63;
    out[(size_t)(tc + r) * R + (tr + c)] = f2bf(tile[c][r]);
  }
}

// ---------------- gemm1: 256x256, BK=64, 8 waves, true 8-phase schedule -----
// LDS per buffer: A,B each [2 ks][256 rows][32 k] bf16 (k-split halves are
// contiguous 16KB stage units).  Phase q of tile t:
//   ph0: read B.k0 frags (4) + A.k0 mf0-3 (4); stage (t+1).A.k1 -> other buf
//   ph1: read A.k0 mf4-7 (4);                  stage (t+1).B.k1 -> other buf
//   ph2: read B.k1 (4) + A.k1 mf0-3 (4);       stage (t+2).B.k0 -> this buf
//   ph3: read A.k1 mf4-7 (4);                  stage (t+2).A.k0 -> this buf
// each phase: reads; stage; barrier; lgkmcnt(0); setprio(1); 16 MFMA; setprio(0); barrier.
// Region safety: k0 regions of this buf are last read at ph0/ph1; stages into
// them issue at ph2/ph3 (after the ph1/ph2 barriers).  Other buf is fully free.
// vmcnt(4) once per tile at entry (the 2 newest units, targets t+2, stay in
// flight); vmcnt(0) only at the last tile.  Min consumption lead = 5 phases.
__global__ __launch_bounds__(512, 2)
void k_gemm1(const unsigned short* __restrict__ A,
             const unsigned short* __restrict__ Bt,
             const float* __restrict__ bias,
             unsigned short* __restrict__ Cbf,
             int M, int N, int K) {
  __shared__ unsigned short sA[2][16384];   // [buf][ks*8192 + row*32 + k8*8]
  __shared__ unsigned short sB[2][16384];
  const int nbn = N >> 8;
  const int nwg = (M >> 8) * nbn;
  int wg = blockIdx.x;
  const int cpx = nwg >> 3;                 // nwg % 8 == 0
  wg = (wg & 7) * cpx + (wg >> 3);
  const int bm = wg / nbn, bn = wg - bm * nbn;
  const int tid = threadIdx.x;
  const int lane = tid & 63, wave = tid >> 6;
  const int wr = wave >> 2, wc = wave & 3;  // 2 (M) x 4 (N)
  const int lc = lane & 15, lr = lane >> 4;

  // stage source addressing (inverse-swizzled): dest elem = ks*8192 + r*4096 + tid*8
  //   row = r*128 + (tid>>2), phys slot = tid&3, logical chunk = (tid&3)^(row&3)
  const int srow = tid >> 2;
  const int schunk = (tid & 3) ^ (srow & 3);
  const unsigned short* sa0 = A + (size_t)(bm * 256 + srow) * K + schunk * 8;
  const unsigned short* sa1 = sa0 + (size_t)128 * K;
  const unsigned short* sb0 = Bt + (size_t)(bn * 256 + srow) * K + schunk * 8;
  const unsigned short* sb1 = sb0 + (size_t)128 * K;

  // one stage unit (16KB): 2 gloads; koff = tile*64 + ks*32
  auto stageA = [&](int bb, int ks, int koff) {
    gload16(sa0 + koff, &sA[bb][ks * 8192 + tid * 8]);
    gload16(sa1 + koff, &sA[bb][ks * 8192 + 4096 + tid * 8]);
  };
  auto stageB = [&](int bb, int ks, int koff) {
    gload16(sb0 + koff, &sB[bb][ks * 8192 + tid * 8]);
    gload16(sb1 + koff, &sB[bb][ks * 8192 + 4096 + tid * 8]);
  };

  // fragment read offsets (elements): row = base + lc, slot = lr ^ (lc&3)
  const int rslot = (lr ^ (lc & 3)) * 8;

  f32x4 acc[8][4];
  const f32x4 zero = {0.f, 0.f, 0.f, 0.f};
#pragma unroll
  for (int m = 0; m < 8; ++m)
#pragma unroll
    for (int n = 0; n < 4; ++n) acc[m][n] = zero;

  const int NT = K >> 6;   // 40

  // prologue: 0.Ak0, 0.Bk0, 0.Ak1, 0.Bk1, 1.Ak0, 1.Bk0  (12 loads/thread)
  stageA(0, 0, 0);
  stageB(0, 0, 0);
  stageA(0, 1, 32);
  stageB(0, 1, 32);
  stageA(1, 0, 64);
  stageB(1, 0, 64);
  asm volatile("s_waitcnt vmcnt(4)" ::: "memory");
  __builtin_amdgcn_s_barrier();

  bf16x8 af[4], bf[4];
  for (int t = 0; t < NT; ++t) {
    const int b = t & 1, ob = b ^ 1;
    const bool st1 = (t + 1) < NT, st2 = (t + 2) < NT;
    const unsigned short* cA = &sA[b][0];
    const unsigned short* cB = &sB[b][0];

    // ---- phase 0: B.k0 all + A.k0 mf0-3 ----
#pragma unroll
    for (int nf = 0; nf < 4; ++nf)
      bf[nf] = *(const bf16x8*)&cB[(wc * 64 + nf * 16 + lc) * 32 + rslot];
#pragma unroll
    for (int mf = 0; mf < 4; ++mf)
      af[mf] = *(const bf16x8*)&cA[(wr * 128 + mf * 16 + lc) * 32 + rslot];
    if (st1) stageA(ob, 1, (t + 1) * 64 + 32);
    __builtin_amdgcn_s_barrier();
    asm volatile("s_waitcnt lgkmcnt(0)" ::: "memory");
    __builtin_amdgcn_sched_barrier(0);
    __builtin_amdgcn_s_setprio(1);
#pragma unroll
    for (int mf = 0; mf < 4; ++mf)
#pragma unroll
      for (int nf = 0; nf < 4; ++nf)
        acc[mf][nf] = __builtin_amdgcn_mfma_f32_16x16x32_bf16(af[mf], bf[nf], acc[mf][nf], 0, 0, 0);
    __builtin_amdgcn_s_setprio(0);
    __builtin_amdgcn_s_barrier();

    // ---- phase 1: A.k0 mf4-7 ----
#pragma unroll
    for (int mf = 0; mf < 4; ++mf)
      af[mf] = *(const bf16x8*)&cA[(wr * 128 + (mf + 4) * 16 + lc) * 32 + rslot];
    if (st1) stageB(ob, 1, (t + 1) * 64 + 32);
    __builtin_amdgcn_s_barrier();
    asm volatile("s_waitcnt lgkmcnt(0)" ::: "memory");
    __builtin_amdgcn_sched_barrier(0);
    __builtin_amdgcn_s_setprio(1);
#pragma unroll
    for (int mf = 0; mf < 4; ++mf)
#pragma unroll
      for (int nf = 0; nf < 4; ++nf)
        acc[mf + 4][nf] = __builtin_amdgcn_mfma_f32_16x16x32_bf16(af[mf], bf[nf], acc[mf + 4][nf], 0, 0, 0);
    __builtin_amdgcn_s_setprio(0);
    __builtin_amdgcn_s_barrier();

    // ---- phase 2: B.k1 all + A.k1 mf0-3 ----
#pragma unroll
    for (int nf = 0; nf < 4; ++nf)
      bf[nf] = *(const bf16x8*)&cB[8192 + (wc * 64 + nf * 16 + lc) * 32 + rslot];
#pragma unroll
    for (int mf = 0; mf < 4; ++mf)
      af[mf] = *(const bf16x8*)&cA[8192 + (wr * 128 + mf * 16 + lc) * 32 + rslot];
    if (st2) stageB(b, 0, (t + 2) * 64);
    __builtin_amdgcn_s_barrier();
    asm volatile("s_waitcnt lgkmcnt(0)" ::: "memory");
    __builtin_amdgcn_sched_barrier(0);
    __builtin_amdgcn_s_setprio(1);
#pragma unroll
    for (int mf = 0; mf < 4; ++mf)
#pragma unroll
      for (int nf = 0; nf < 4; ++nf)
        acc[mf][nf] = __builtin_amdgcn_mfma_f32_16x16x32_bf16(af[mf], bf[nf], acc[mf][nf], 0, 0, 0);
    __builtin_amdgcn_s_setprio(0);
    __builtin_amdgcn_s_barrier();

    // ---- phase 3: A.k1 mf4-7 ----
#pragma unroll
    for (int mf = 0; mf < 4; ++mf)
      af[mf] = *(const bf16x8*)&cA[8192 + (wr * 128 + (mf + 4) * 16 + lc) * 32 + rslot];
    if (st2) stageA(b, 0, (t + 2) * 64);
    __builtin_amdgcn_s_barrier();
    asm volatile("s_waitcnt lgkmcnt(0)" ::: "memory");
    __builtin_amdgcn_sched_barrier(0);
    __builtin_amdgcn_s_setprio(1);
#pragma unroll
    for (int mf = 0; mf < 4; ++mf)
#pragma unroll
      for (int nf = 0; nf < 4; ++nf)
        acc[mf + 4][nf] = __builtin_amdgcn_mfma_f32_16x16x32_bf16(af[mf], bf[nf], acc[mf + 4][nf], 0, 0, 0);
    __builtin_amdgcn_s_setprio(0);
    // tile boundary: counted entry wait for next tile + shared barrier
    if (st2)      asm volatile("s_waitcnt vmcnt(4)" ::: "memory");
    else          asm volatile("s_waitcnt vmcnt(0)" ::: "memory");
    __builtin_amdgcn_s_barrier();
  }

  // epilogue: bias + bf16 store
  const int rowb = bm * 256 + wr * 128;
  const int colb = bn * 256 + wc * 64;
#pragma unroll
  for (int nf = 0; nf < 4; ++nf) {
    const int col = colb + nf * 16 + lc;
    const float bv = bias[col];
#pragma unroll
    for (int mf = 0; mf < 8; ++mf) {
#pragma unroll
      for (int jj = 0; jj < 4; ++jj) {
        const int row = rowb + mf * 16 + lr * 4 + jj;
        Cbf[(size_t)row * N + col] = f2bf(acc[mf][nf][jj] + bv);
      }
    }
  }
}

// ---------------- legacy 128x128 GEMM (gemm2): 4-deep, counted vmcnt --------
template <int BM>
__global__ __launch_bounds__(BM / 32 * 64, 2)
void k_gemm_t(const unsigned short* __restrict__ A,
              const unsigned short* __restrict__ Bt,
              const float* __restrict__ bias,
              unsigned short* __restrict__ Cbf,
              float* __restrict__ Cf,
              int M, int N, int K, int out_f32) {
  constexpr int NW = BM / 32;
  constexpr int NCW = NW / 2;
  constexpr int MF = BM / 32;
  constexpr int TE = BM * 32;
  __shared__ unsigned short sA[4][TE];
  __shared__ unsigned short sB[4][TE];
  const int nbn = N / BM;
  const int nwg = (M / BM) * nbn;
  int wg = blockIdx.x;
  const int cpx = nwg >> 3;
  wg = (wg & 7) * cpx + (wg >> 3);
  const int bm = wg / nbn, bn = wg - bm * nbn;
  const int tid = threadIdx.x;
  const int lane = tid & 63, wave = tid >> 6;
  const int wr = wave / NCW, wc = wave % NCW;
  const int lc = lane & 15, lr = lane >> 4;

  const int sub = (lane & 7) ^ (lane >> 3);
  const int rstage = wave * 16 + ((lane >> 3) << 1) + (sub >> 2);
  const int cstage = (sub & 3) * 8;
  const unsigned short* Agp = A + (size_t)(bm * BM + rstage) * K + cstage;
  const unsigned short* Bgp = Bt + (size_t)(bn * BM + rstage) * K + cstage;
  const size_t halfoff = (size_t)(BM / 2) * K;

  const int loff = ((lc >> 1) << 7) + (((((lc & 1) << 2) | lr) ^ (lc >> 1)) << 4);

  f32x4 acc[MF][4];
  const f32x4 zero = {0.f, 0.f, 0.f, 0.f};
#pragma unroll
  for (int m = 0; m < MF; ++m)
#pragma unroll
    for (int n = 0; n < 4; ++n) acc[m][n] = zero;

  auto stage = [&](int buf, int t) {
    gload16(Agp + t * 32, &sA[buf][wave * 512]);
    gload16(Agp + halfoff + t * 32, &sA[buf][BM * 16 + wave * 512]);
    gload16(Bgp + t * 32, &sB[buf][wave * 512]);
    gload16(Bgp + halfoff + t * 32, &sB[buf][BM * 16 + wave * 512]);
  };

  const int NT = K >> 5;
#pragma unroll
  for (int t = 0; t < 3; ++t) stage(t, t);

  const int nj = NT >> 2;
  for (int j = 0; j < nj; ++j) {
#pragma unroll
    for (int to = 0; to < 4; ++to) {
      const int t = (j << 2) + to;
      if (t < NT - 2)       asm volatile("s_waitcnt vmcnt(8)" ::: "memory");
      else if (t == NT - 2) asm volatile("s_waitcnt vmcnt(4)" ::: "memory");
      else                  asm volatile("s_waitcnt vmcnt(0)" ::: "memory");
      __builtin_amdgcn_s_barrier();
      asm volatile("" ::: "memory");
      __builtin_amdgcn_sched_barrier(0);

      const char* bufA = (const char*)&sA[to][0];
      const char* bufB = (const char*)&sB[to][0];
      bf16x8 bfr[4], af[MF];
#pragma unroll
      for (int ni = 0; ni < 4; ++ni)
        bfr[ni] = *(const bf16x8*)(bufB + ((wc * 64 + ni * 16) << 6) + loff);
#pragma unroll
      for (int mi = 0; mi < MF; ++mi)
        af[mi] = *(const bf16x8*)(bufA + ((wr * (BM / 2) + mi * 16) << 6) + loff);

      if (t + 3 < NT) stage((to + 3) & 3, t + 3);

      __builtin_amdgcn_s_setprio(1);
#pragma unroll
      for (int mi = 0; mi < MF; ++mi)
#pragma unroll
        for (int ni = 0; ni < 4; ++ni)
          acc[mi][ni] = __builtin_amdgcn_mfma_f32_16x16x32_bf16(af[mi], bfr[ni], acc[mi][ni], 0, 0, 0);
      __builtin_amdgcn_s_setprio(0);
    }
  }

  const int rowb = bm * BM + wr * (BM / 2);
  const int colb = bn * BM + wc * 64;
#pragma unroll
  for (int ni = 0; ni < 4; ++ni) {
    const int col = colb + ni * 16 + lc;
    const float bv = bias[col];
#pragma unroll
    for (int mf = 0; mf < MF; ++mf) {
#pragma unroll
      for (int jj = 0; jj < 4; ++jj) {
        const int row = rowb + mf * 16 + lr * 4 + jj;
        const float v = acc[mf][ni][jj] + bv;
        if (out_f32) Cf[(size_t)row * N + col] = v;
        else Cbf[(size_t)row * N + col] = f2bf(v);
      }
    }
  }
}

// ---------------- RoPE + head split: qkv -> Q (scaled), K, V^T ----------------
__global__ __launch_bounds__(256) void k_rope(const unsigned short* __restrict__ qkv,
                                              unsigned short* __restrict__ Qw,
                                              unsigned short* __restrict__ Kw,
                                              unsigned short* __restrict__ Vt) {
  const int blk = blockIdx.x;
  const int sc = blk & 31;
  const int bh = blk >> 5;
  const int b = bh >> 5, h = bh & 31;
  const int s0 = sc * 64;
  __shared__ float cs0[64][16], sn0[64][16];
  __shared__ unsigned short vbuf[64][82];
  const int tid = threadIdx.x;
  for (int i = tid; i < 64 * 16; i += 256) {
    int sl = i >> 4, fi = i & 15;
    float ang = (float)(s0 + sl) * __expf(-(float)fi * 0.575646273248511421f);
    cs0[sl][fi] = cosf(ang);
    sn0[sl][fi] = sinf(ang);
  }
  __syncthreads();
  const size_t row0 = (size_t)(b * S_LEN + s0) * QKV_N;
  const size_t obase = ((size_t)bh * S_LEN + s0) * DPAD;
  for (int i = tid; i < 64 * DPAD; i += 256) {
    int sl = i / DPAD, d = i - sl * DPAD;
    float qv = 0.f, kv = 0.f;
    if (d < HD) {
      const unsigned short* rp = qkv + row0 + (size_t)sl * QKV_N + h * HD;
      float q = bf2f(rp[d]), k = bf2f(rp[HIDDEN + d]);
      if (d < 16) {
        float c = cs0[sl][d], s = sn0[sl][d];
        float q2 = bf2f(rp[d + 16]), k2 = bf2f(rp[HIDDEN + d + 16]);
        qv = q * c - q2 * s;
        kv = k * c - k2 * s;
      } else if (d < 32) {
        float c = cs0[sl][d - 16], s = sn0[sl][d - 16];
        float q1 = bf2f(rp[d - 16]), k1 = bf2f(rp[HIDDEN + d - 16]);
        qv = q * c + q1 * s;
        kv = k * c + k1 * s;
      } else {
        qv = q; kv = k;
      }
    }
    Qw[obase + (size_t)sl * DPAD + d] = f2bf(qv * 0.111803398874989485f); // * 80^-0.5
    Kw[obase + (size_t)sl * DPAD + d] = f2bf(kv);
  }
  for (int i = tid; i < 64 * HD; i += 256) {
    int sl = i / HD, d = i - sl * HD;
    vbuf[sl][d] = qkv[row0 + (size_t)sl * QKV_N + 2 * HIDDEN + h * HD + d];
  }
  __syncthreads();
  const size_t vtb = (size_t)bh * DPAD * S_LEN + s0;
  for (int i = tid; i < DPAD * 64; i += 256) {
    int d = i >> 6, sl = i & 63;
    Vt[vtb + (size_t)d * S_LEN + sl] = (d < HD) ? vbuf[sl][d] : (unsigned short)0;
  }
}

// ---------------- flash attention (causal), QBLK=128, KVBLK=64 ----------------
__global__ __launch_bounds__(256, 2) void k_attn(const unsigned short* __restrict__ Qw,
                                                 const unsigned short* __restrict__ Kw,
                                                 const unsigned short* __restrict__ Vt,
                                                 unsigned short* __restrict__ O) {
  __shared__ unsigned short sK[2][64 * 104];
  __shared__ unsigned short sV[2][80 * 72];
  __shared__ unsigned short sP[4][16 * 72];
  const int p = blockIdx.x;
  const int bh = blockIdx.y;
  const int b = bh >> 5, h = bh & 31;
  const int tid = threadIdx.x;
  const int wave = tid >> 6, lane = tid & 63;
  const int lr = lane >> 4, lc = lane & 15;
  unsigned short* Pw = &sP[wave][0];

  const unsigned short* Kh = Kw + (size_t)bh * S_LEN * DPAD;
  const unsigned short* Vh = Vt + (size_t)bh * DPAD * S_LEN;
  const unsigned short* Qh = Qw + (size_t)bh * S_LEN * DPAD;

  const int kr = tid >> 2, kc = (tid & 3) * 24;
  const int vr = tid >> 3, vc = (tid & 7) * 8;

  u16x8 kst0, kst1, kst2, vst0, vst1, vst2;
  auto gload = [&](int t) {
    const unsigned short* Kg = Kh + ((size_t)(t * 64 + kr)) * DPAD + kc;
    kst0 = *(const u16x8*)(Kg);
    kst1 = *(const u16x8*)(Kg + 8);
    kst2 = *(const u16x8*)(Kg + 16);
    const unsigned short* Vg = Vh + (size_t)vr * S_LEN + t * 64 + vc;
    vst0 = *(const u16x8*)(Vg);
    vst1 = *(const u16x8*)(Vg + 32 * S_LEN);
    if (tid < 128) vst2 = *(const u16x8*)(Vg + (size_t)64 * S_LEN);
  };
  auto swrite = [&](int buf) {
    *(u16x8*)&sK[buf][kr * 104 + kc] = kst0;
    *(u16x8*)&sK[buf][kr * 104 + kc + 8] = kst1;
    *(u16x8*)&sK[buf][kr * 104 + kc + 16] = kst2;
    *(u16x8*)&sV[buf][vr * 72 + vc] = vst0;
    *(u16x8*)&sV[buf][(vr + 32) * 72 + vc] = vst1;
    if (tid < 128) *(u16x8*)&sV[buf][(vr + 64) * 72 + vc] = vst2;
  };

  const f32x4 zero = {0.f, 0.f, 0.f, 0.f};

#pragma unroll 1
  for (int qi = 0; qi < 2; ++qi) {
    const int qt = qi ? (15 - p) : p;
    const int nt = 2 * qt + 2;
    const int wbase = qt * 128 + wave * 32;

    bf16x8 qf[2][3];
#pragma unroll
    for (int m = 0; m < 2; ++m)
#pragma unroll
      for (int ks = 0; ks < 3; ++ks)
        qf[m][ks] = *(const bf16x8*)&Qh[(size_t)(wbase + m * 16 + lc) * DPAD + ks * 32 + lr * 8];

    f32x4 oacc[2][5];
#pragma unroll
    for (int m = 0; m < 2; ++m)
#pragma unroll
      for (int n = 0; n < 5; ++n) oacc[m][n] = zero;
    float mrun[2] = {-1e30f, -1e30f}, lrun[2] = {0.f, 0.f};

    gload(0);
    __syncthreads();
    swrite(0);
    int cur = 0;

#pragma unroll 1
    for (int t = 0; t < nt; ++t) {
      __syncthreads();
      if (t + 1 < nt) gload(t + 1);
      const int ktb = t * 64;
      const bool act0 = ktb <= wbase + 15;
      const bool act1 = ktb <= wbase + 31;
      if (act1) {
        const unsigned short* Kc = sK[cur];
        const unsigned short* Vc = sV[cur];
        f32x4 sf[2][4];
#pragma unroll
        for (int n = 0; n < 4; ++n) {
          sf[0][n] = zero; sf[1][n] = zero;
#pragma unroll
          for (int ks = 0; ks < 3; ++ks) {
            bf16x8 kf = *(const bf16x8*)&Kc[(n * 16 + lc) * 104 + ks * 32 + lr * 8];
            if (act0) sf[0][n] = __builtin_amdgcn_mfma_f32_16x16x32_bf16(kf, qf[0][ks], sf[0][n], 0, 0, 0);
            sf[1][n] = __builtin_amdgcn_mfma_f32_16x16x32_bf16(kf, qf[1][ks], sf[1][n], 0, 0, 0);
          }
        }
        bf16x8 vf[5][2];
#pragma unroll
        for (int n = 0; n < 5; ++n)
#pragma unroll
          for (int ks = 0; ks < 2; ++ks)
            vf[n][ks] = *(const bf16x8*)&Vc[(n * 16 + lc) * 72 + ks * 32 + lr * 8];
#pragma unroll
        for (int m = 0; m < 2; ++m) {
          if (m == 0 && !act0) continue;
          const int qrow0 = wbase + m * 16;
          if (ktb + 63 > qrow0) {
#pragma unroll
            for (int n = 0; n < 4; ++n)
#pragma unroll
              for (int j = 0; j < 4; ++j)
                if (ktb + n * 16 + lr * 4 + j > qrow0 + lc) sf[m][n][j] = -1e30f;
          }
          float t0 = sf[m][0][0];
#pragma unroll
          for (int n = 0; n < 4; ++n)
#pragma unroll
            for (int j = 0; j < 4; ++j) t0 = fmaxf(t0, sf[m][n][j]);
          t0 = fmaxf(t0, __shfl_xor(t0, 16));
          t0 = fmaxf(t0, __shfl_xor(t0, 32));
          const float nm = fmaxf(mrun[m], t0);
          const float corrq = __expf(mrun[m] - nm);
          mrun[m] = nm;
          float ps = 0.f;
#pragma unroll
          for (int n = 0; n < 4; ++n)
#pragma unroll
            for (int j = 0; j < 4; ++j) {
              float e = __expf(sf[m][n][j] - nm);
              sf[m][n][j] = e;
              ps += e;
            }
          ps += __shfl_xor(ps, 16);
          ps += __shfl_xor(ps, 32);
          lrun[m] = lrun[m] * corrq + ps;
          float cj[4];
#pragma unroll
          for (int j = 0; j < 4; ++j) cj[j] = __shfl(corrq, lr * 4 + j, 16);
#pragma unroll
          for (int n = 0; n < 5; ++n)
#pragma unroll
            for (int j = 0; j < 4; ++j) oacc[m][n][j] *= cj[j];
#pragma unroll
          for (int n = 0; n < 4; ++n) {
            unsigned lo = (unsigned)f2bf(sf[m][n][0]) | ((unsigned)f2bf(sf[m][n][1]) << 16);
            unsigned hi = (unsigned)f2bf(sf[m][n][2]) | ((unsigned)f2bf(sf[m][n][3]) << 16);
            uint2 u; u.x = lo; u.y = hi;
            *(uint2*)&Pw[lc * 72 + n * 16 + lr * 4] = u;
          }
          asm volatile("" ::: "memory");
          bf16x8 pa0 = *(const bf16x8*)&Pw[lc * 72 + lr * 8];
          bf16x8 pa1 = *(const bf16x8*)&Pw[lc * 72 + 32 + lr * 8];
#pragma unroll
          for (int n = 0; n < 5; ++n) {
            oacc[m][n] = __builtin_amdgcn_mfma_f32_16x16x32_bf16(pa0, vf[n][0], oacc[m][n], 0, 0, 0);
            oacc[m][n] = __builtin_amdgcn_mfma_f32_16x16x32_bf16(pa1, vf[n][1], oacc[m][n], 0, 0, 0);
          }
          asm volatile("" ::: "memory");
        }
      }
      if (t + 1 < nt) swrite(cur ^ 1);
      cur ^= 1;
    }

#pragma unroll
    for (int m = 0; m < 2; ++m) {
      float linv[4];
#pragma unroll
      for (int j = 0; j < 4; ++j) {
        float lj = __shfl(lrun[m], lr * 4 + j, 16);
        linv[j] = 1.f / lj;
      }
      const int q0 = wbase + m * 16 + lr * 4;
#pragma unroll
      for (int n = 0; n < 5; ++n) {
        const int d = n * 16 + lc;
#pragma unroll
        for (int j = 0; j < 4; ++j)
          O[((size_t)(b * S_LEN) + q0 + j) * HIDDEN + h * HD + d] = f2bf(oacc[m][n][j] * linv[j]);
      }
    }
  }
}

extern "C" void kernel_launch(void* const* d_in, const int* in_sizes, int n_in,
                              void* d_out, int out_size, void* d_ws, size_t ws_size,
                              hipStream_t stream) {
  (void)in_sizes; (void)n_in; (void)out_size; (void)ws_size;
  const float* hidden  = (const float*)d_in[1];
  const float* w_qkv   = (const float*)d_in[2];
  const float* b_qkv   = (const float*)d_in[3];
  const float* w_dense = (const float*)d_in[4];
  const float* b_dense = (const float*)d_in[5];
  char* ws = (char*)d_ws;
  unsigned short* Abf   = (unsigned short*)(ws + 0);          // 4096x2560 bf16
  unsigned short* Wqkvt = (unsigned short*)(ws + 20971520);   // 7680x2560 bf16
  unsigned short* Wdt   = (unsigned short*)(ws + 60293120);   // 2560x2560 bf16
  unsigned short* QKVb  = (unsigned short*)(ws + 73400320);   // 4096x7680 bf16
  unsigned short* Qw    = (unsigned short*)(ws + 136314880);  // 64x2048x96 bf16
  unsigned short* Kw    = (unsigned short*)(ws + 161480704);
  unsigned short* Vt    = (unsigned short*)(ws + 186646528);
  unsigned short* Obf   = (unsigned short*)(ws + 211812352);  // 4096x2560 bf16

  k_cvt<<<10240, 256, 0, stream>>>(hidden, Abf, 2621440);
  k_transpose_bf16<<<dim3(120, 40), 256, 0, stream>>>(w_qkv, Wqkvt, 2560, 7680);
  k_transpose_bf16<<<dim3(40, 40), 256, 0, stream>>>(w_dense, Wdt, 2560, 2560);
  k_gemm1<<<480, 512, 0, stream>>>(Abf, Wqkvt, b_qkv, QKVb, 4096, 7680, 2560);
  k_rope<<<2048, 256, 0, stream>>>(QKVb, Qw, Kw, Vt);
  k_attn<<<dim3(8, 64), 256, 0, stream>>>(Qw, Kw, Vt, Obf);
  k_gemm_t<128><<<640, 256, 0, stream>>>(Obf, Wdt, b_dense, nullptr, (float*)d_out, 4096, 2560, 2560, 1);
}

// Round 7
// 444.437 us; speedup vs baseline: 1.0206x; 1.0206x over previous
//
#include <hip/hip_runtime.h>

#define S_LEN 2048
#define NHEAD 32
#define HD 80
#define DPAD 96
#define HIDDEN 2560
#define QKV_N 7680

typedef __attribute__((ext_vector_type(8))) short bf16x8;
typedef __attribute__((ext_vector_type(8))) unsigned short u16x8;
typedef __attribute__((ext_vector_type(4))) float f32x4;

__device__ __forceinline__ unsigned short f2bf(float f) {
  unsigned int u = __float_as_uint(f);
  u += 0x7fffu + ((u >> 16) & 1u);   // RNE
  return (unsigned short)(u >> 16);
}
__device__ __forceinline__ float bf2f(unsigned short h) {
  return __uint_as_float(((unsigned int)h) << 16);
}

__device__ __forceinline__ void gload16(const void* g, void* l) {
  __builtin_amdgcn_global_load_lds((const __attribute__((address_space(1))) void*)g,
                                   (__attribute__((address_space(3))) void*)l, 16, 0, 0);
}

// ---------------- fp32 -> bf16 elementwise ----------------
__global__ __launch_bounds__(256) void k_cvt(const float* __restrict__ in,
                                             unsigned short* __restrict__ out, int n4) {
  int i = blockIdx.x * 256 + threadIdx.x;
  if (i >= n4) return;
  float4 v = reinterpret_cast<const float4*>(in)[i];
  ushort4 o;
  o.x = f2bf(v.x); o.y = f2bf(v.y); o.z = f2bf(v.z); o.w = f2bf(v.w);
  reinterpret_cast<ushort4*>(out)[i] = o;
}

// ---------------- fp32 (R x C) -> bf16 transposed (C x R) ----------------
__global__ __launch_bounds__(256) void k_transpose_bf16(const float* __restrict__ in,
                                                        unsigned short* __restrict__ out,
                                                        int R, int C) {
  __shared__ float tile[64][65];
  int tc = blockIdx.x * 64, tr = blockIdx.y * 64;
  for (int i = threadIdx.x; i < 64 * 64; i += 256) {
    int r = i >> 6, c = i & 63;
    tile[r][c] = in[(size_t)(tr + r) * C + (tc + c)];
  }
  __syncthreads();
  for (int i = threadIdx.x; i < 64 * 64; i += 256) {
    int r = i >> 6, c = i & 63;
    out[(size_t)(tc + r) * R + (tr + c)] = f2bf(tile[c][r]);
  }
}

// ---------------- gemm1: 256x256, BK=64, 8 waves, 4-phase/K-tile schedule ----
// LDS per buffer: A,B each [2 ks][256 rows][32 k] bf16; each ks-half is a
// [256][32] tile in the R4-VERIFIED swizzled layout (0 bank conflicts):
//   logical (row, chunk8) at super-row sr=row>>1, slot8 = (((row&1)<<2)|chunk)^(sr&7).
// Stage via inverse-swizzled global source (rstage/cstage), dest linear
// ks*8192 + {0,4096} + wave*512 elems.  Read via loff (requires row-base % 16 == 0).
// Phases per tile t (buf b = t&1, ob = b^1):
//   ph0: read B.k0(4) + A.k0 mf0-3(4); stage (t+1).A.k1 -> ob
//   ph1: read A.k0 mf4-7(4);           stage (t+1).B.k1 -> ob
//   ph2: read B.k1(4) + A.k1 mf0-3(4); stage (t+2).B.k0 -> b
//   ph3: read A.k1 mf4-7(4);           stage (t+2).A.k0 -> b
// each: reads; stage; barrier; lgkmcnt(0); sched_barrier; setprio(1); 16 MFMA;
// setprio(0); barrier.  Tile boundary: vmcnt(4) (keeps the 2 newest units --
// targets t+2 -- in flight); vmcnt(0) only at the end.
__global__ __launch_bounds__(512, 2)
void k_gemm1(const unsigned short* __restrict__ A,
             const unsigned short* __restrict__ Bt,
             const float* __restrict__ bias,
             unsigned short* __restrict__ Cbf,
             int M, int N, int K) {
  __shared__ unsigned short sA[2][16384];
  __shared__ unsigned short sB[2][16384];
  const int nbn = N >> 8;
  const int nwg = (M >> 8) * nbn;
  int wg = blockIdx.x;
  const int cpx = nwg >> 3;                 // nwg % 8 == 0
  wg = (wg & 7) * cpx + (wg >> 3);
  const int bm = wg / nbn, bn = wg - bm * nbn;
  const int tid = threadIdx.x;
  const int lane = tid & 63, wave = tid >> 6;
  const int wr = wave >> 2, wc = wave & 3;  // 2 (M) x 4 (N)
  const int lc = lane & 15, lr = lane >> 4;

  // R4-verified staging source (inverse-swizzled), per [256][32] half
  const int sub = (lane & 7) ^ (lane >> 3);
  const int rstage = wave * 16 + ((lane >> 3) << 1) + (sub >> 2);
  const int cstage = (sub & 3) * 8;
  const unsigned short* Agp = A + (size_t)(bm * 256 + rstage) * K + cstage;
  const unsigned short* Bgp = Bt + (size_t)(bn * 256 + rstage) * K + cstage;
  const size_t halfoff = (size_t)128 * K;

  // R4-verified fragment-read lane offset (bytes) within a half
  const int loff = ((lc >> 1) << 7) + (((((lc & 1) << 2) | lr) ^ (lc >> 1)) << 4);

  auto stageA = [&](int bb, int ks, int koff) {
    gload16(Agp + koff, &sA[bb][ks * 8192 + wave * 512]);
    gload16(Agp + halfoff + koff, &sA[bb][ks * 8192 + 4096 + wave * 512]);
  };
  auto stageB = [&](int bb, int ks, int koff) {
    gload16(Bgp + koff, &sB[bb][ks * 8192 + wave * 512]);
    gload16(Bgp + halfoff + koff, &sB[bb][ks * 8192 + 4096 + wave * 512]);
  };

  f32x4 acc[8][4];
  const f32x4 zero = {0.f, 0.f, 0.f, 0.f};
#pragma unroll
  for (int m = 0; m < 8; ++m)
#pragma unroll
    for (int n = 0; n < 4; ++n) acc[m][n] = zero;

  const int NT = K >> 6;   // 40

  // prologue: 0.Ak0, 0.Bk0, 0.Ak1, 0.Bk1, 1.Ak0, 1.Bk0
  stageA(0, 0, 0);
  stageB(0, 0, 0);
  stageA(0, 1, 32);
  stageB(0, 1, 32);
  stageA(1, 0, 64);
  stageB(1, 0, 64);
  asm volatile("s_waitcnt vmcnt(4)" ::: "memory");
  __builtin_amdgcn_s_barrier();

  bf16x8 af[4], bf[4];
  for (int t = 0; t < NT; ++t) {
    const int b = t & 1, ob = b ^ 1;
    const bool st1 = (t + 1) < NT, st2 = (t + 2) < NT;
    const char* cA0 = (const char*)&sA[b][0];
    const char* cB0 = (const char*)&sB[b][0];
    const char* cA1 = (const char*)&sA[b][8192];
    const char* cB1 = (const char*)&sB[b][8192];

    // ---- phase 0 ----
#pragma unroll
    for (int nf = 0; nf < 4; ++nf)
      bf[nf] = *(const bf16x8*)(cB0 + ((wc * 64 + nf * 16) << 6) + loff);
#pragma unroll
    for (int mf = 0; mf < 4; ++mf)
      af[mf] = *(const bf16x8*)(cA0 + ((wr * 128 + mf * 16) << 6) + loff);
    if (st1) stageA(ob, 1, (t + 1) * 64 + 32);
    __builtin_amdgcn_s_barrier();
    asm volatile("s_waitcnt lgkmcnt(0)" ::: "memory");
    __builtin_amdgcn_sched_barrier(0);
    __builtin_amdgcn_s_setprio(1);
#pragma unroll
    for (int mf = 0; mf < 4; ++mf)
#pragma unroll
      for (int nf = 0; nf < 4; ++nf)
        acc[mf][nf] = __builtin_amdgcn_mfma_f32_16x16x32_bf16(af[mf], bf[nf], acc[mf][nf], 0, 0, 0);
    __builtin_amdgcn_s_setprio(0);
    __builtin_amdgcn_s_barrier();

    // ---- phase 1 ----
#pragma unroll
    for (int mf = 0; mf < 4; ++mf)
      af[mf] = *(const bf16x8*)(cA0 + ((wr * 128 + (mf + 4) * 16) << 6) + loff);
    if (st1) stageB(ob, 1, (t + 1) * 64 + 32);
    __builtin_amdgcn_s_barrier();
    asm volatile("s_waitcnt lgkmcnt(0)" ::: "memory");
    __builtin_amdgcn_sched_barrier(0);
    __builtin_amdgcn_s_setprio(1);
#pragma unroll
    for (int mf = 0; mf < 4; ++mf)
#pragma unroll
      for (int nf = 0; nf < 4; ++nf)
        acc[mf + 4][nf] = __builtin_amdgcn_mfma_f32_16x16x32_bf16(af[mf], bf[nf], acc[mf + 4][nf], 0, 0, 0);
    __builtin_amdgcn_s_setprio(0);
    __builtin_amdgcn_s_barrier();

    // ---- phase 2 ----
#pragma unroll
    for (int nf = 0; nf < 4; ++nf)
      bf[nf] = *(const bf16x8*)(cB1 + ((wc * 64 + nf * 16) << 6) + loff);
#pragma unroll
    for (int mf = 0; mf < 4; ++mf)
      af[mf] = *(const bf16x8*)(cA1 + ((wr * 128 + mf * 16) << 6) + loff);
    if (st2) stageB(b, 0, (t + 2) * 64);
    __builtin_amdgcn_s_barrier();
    asm volatile("s_waitcnt lgkmcnt(0)" ::: "memory");
    __builtin_amdgcn_sched_barrier(0);
    __builtin_amdgcn_s_setprio(1);
#pragma unroll
    for (int mf = 0; mf < 4; ++mf)
#pragma unroll
      for (int nf = 0; nf < 4; ++nf)
        acc[mf][nf] = __builtin_amdgcn_mfma_f32_16x16x32_bf16(af[mf], bf[nf], acc[mf][nf], 0, 0, 0);
    __builtin_amdgcn_s_setprio(0);
    __builtin_amdgcn_s_barrier();

    // ---- phase 3 ----
#pragma unroll
    for (int mf = 0; mf < 4; ++mf)
      af[mf] = *(const bf16x8*)(cA1 + ((wr * 128 + (mf + 4) * 16) << 6) + loff);
    if (st2) stageA(b, 0, (t + 2) * 64);
    __builtin_amdgcn_s_barrier();
    asm volatile("s_waitcnt lgkmcnt(0)" ::: "memory");
    __builtin_amdgcn_sched_barrier(0);
    __builtin_amdgcn_s_setprio(1);
#pragma unroll
    for (int mf = 0; mf < 4; ++mf)
#pragma unroll
      for (int nf = 0; nf < 4; ++nf)
        acc[mf + 4][nf] = __builtin_amdgcn_mfma_f32_16x16x32_bf16(af[mf], bf[nf], acc[mf + 4][nf], 0, 0, 0);
    __builtin_amdgcn_s_setprio(0);
    if (st2)      asm volatile("s_waitcnt vmcnt(4)" ::: "memory");
    else          asm volatile("s_waitcnt vmcnt(0)" ::: "memory");
    __builtin_amdgcn_s_barrier();
  }

  // epilogue: bias + bf16 store
  const int rowb = bm * 256 + wr * 128;
  const int colb = bn * 256 + wc * 64;
#pragma unroll
  for (int nf = 0; nf < 4; ++nf) {
    const int col = colb + nf * 16 + lc;
    const float bv = bias[col];
#pragma unroll
    for (int mf = 0; mf < 8; ++mf) {
#pragma unroll
      for (int jj = 0; jj < 4; ++jj) {
        const int row = rowb + mf * 16 + lr * 4 + jj;
        Cbf[(size_t)row * N + col] = f2bf(acc[mf][nf][jj] + bv);
      }
    }
  }
}

// ---------------- legacy 128x128 GEMM (gemm2): 4-deep, counted vmcnt --------
template <int BM>
__global__ __launch_bounds__(BM / 32 * 64, 2)
void k_gemm_t(const unsigned short* __restrict__ A,
              const unsigned short* __restrict__ Bt,
              const float* __restrict__ bias,
              unsigned short* __restrict__ Cbf,
              float* __restrict__ Cf,
              int M, int N, int K, int out_f32) {
  constexpr int NW = BM / 32;
  constexpr int NCW = NW / 2;
  constexpr int MF = BM / 32;
  constexpr int TE = BM * 32;
  __shared__ unsigned short sA[4][TE];
  __shared__ unsigned short sB[4][TE];
  const int nbn = N / BM;
  const int nwg = (M / BM) * nbn;
  int wg = blockIdx.x;
  const int cpx = nwg >> 3;
  wg = (wg & 7) * cpx + (wg >> 3);
  const int bm = wg / nbn, bn = wg - bm * nbn;
  const int tid = threadIdx.x;
  const int lane = tid & 63, wave = tid >> 6;
  const int wr = wave / NCW, wc = wave % NCW;
  const int lc = lane & 15, lr = lane >> 4;

  const int sub = (lane & 7) ^ (lane >> 3);
  const int rstage = wave * 16 + ((lane >> 3) << 1) + (sub >> 2);
  const int cstage = (sub & 3) * 8;
  const unsigned short* Agp = A + (size_t)(bm * BM + rstage) * K + cstage;
  const unsigned short* Bgp = Bt + (size_t)(bn * BM + rstage) * K + cstage;
  const size_t halfoff = (size_t)(BM / 2) * K;

  const int loff = ((lc >> 1) << 7) + (((((lc & 1) << 2) | lr) ^ (lc >> 1)) << 4);

  f32x4 acc[MF][4];
  const f32x4 zero = {0.f, 0.f, 0.f, 0.f};
#pragma unroll
  for (int m = 0; m < MF; ++m)
#pragma unroll
    for (int n = 0; n < 4; ++n) acc[m][n] = zero;

  auto stage = [&](int buf, int t) {
    gload16(Agp + t * 32, &sA[buf][wave * 512]);
    gload16(Agp + halfoff + t * 32, &sA[buf][BM * 16 + wave * 512]);
    gload16(Bgp + t * 32, &sB[buf][wave * 512]);
    gload16(Bgp + halfoff + t * 32, &sB[buf][BM * 16 + wave * 512]);
  };

  const int NT = K >> 5;
#pragma unroll
  for (int t = 0; t < 3; ++t) stage(t, t);

  const int nj = NT >> 2;
  for (int j = 0; j < nj; ++j) {
#pragma unroll
    for (int to = 0; to < 4; ++to) {
      const int t = (j << 2) + to;
      if (t < NT - 2)       asm volatile("s_waitcnt vmcnt(8)" ::: "memory");
      else if (t == NT - 2) asm volatile("s_waitcnt vmcnt(4)" ::: "memory");
      else                  asm volatile("s_waitcnt vmcnt(0)" ::: "memory");
      __builtin_amdgcn_s_barrier();
      asm volatile("" ::: "memory");
      __builtin_amdgcn_sched_barrier(0);

      const char* bufA = (const char*)&sA[to][0];
      const char* bufB = (const char*)&sB[to][0];
      bf16x8 bfr[4], af[MF];
#pragma unroll
      for (int ni = 0; ni < 4; ++ni)
        bfr[ni] = *(const bf16x8*)(bufB + ((wc * 64 + ni * 16) << 6) + loff);
#pragma unroll
      for (int mi = 0; mi < MF; ++mi)
        af[mi] = *(const bf16x8*)(bufA + ((wr * (BM / 2) + mi * 16) << 6) + loff);

      if (t + 3 < NT) stage((to + 3) & 3, t + 3);

      __builtin_amdgcn_s_setprio(1);
#pragma unroll
      for (int mi = 0; mi < MF; ++mi)
#pragma unroll
        for (int ni = 0; ni < 4; ++ni)
          acc[mi][ni] = __builtin_amdgcn_mfma_f32_16x16x32_bf16(af[mi], bfr[ni], acc[mi][ni], 0, 0, 0);
      __builtin_amdgcn_s_setprio(0);
    }
  }

  const int rowb = bm * BM + wr * (BM / 2);
  const int colb = bn * BM + wc * 64;
#pragma unroll
  for (int ni = 0; ni < 4; ++ni) {
    const int col = colb + ni * 16 + lc;
    const float bv = bias[col];
#pragma unroll
    for (int mf = 0; mf < MF; ++mf) {
#pragma unroll
      for (int jj = 0; jj < 4; ++jj) {
        const int row = rowb + mf * 16 + lr * 4 + jj;
        const float v = acc[mf][ni][jj] + bv;
        if (out_f32) Cf[(size_t)row * N + col] = v;
        else Cbf[(size_t)row * N + col] = f2bf(v);
      }
    }
  }
}

// ---------------- RoPE + head split: qkv -> Q (scaled), K, V^T ----------------
__global__ __launch_bounds__(256) void k_rope(const unsigned short* __restrict__ qkv,
                                              unsigned short* __restrict__ Qw,
                                              unsigned short* __restrict__ Kw,
                                              unsigned short* __restrict__ Vt) {
  const int blk = blockIdx.x;
  const int sc = blk & 31;
  const int bh = blk >> 5;
  const int b = bh >> 5, h = bh & 31;
  const int s0 = sc * 64;
  __shared__ float cs0[64][16], sn0[64][16];
  __shared__ unsigned short vbuf[64][82];
  const int tid = threadIdx.x;
  for (int i = tid; i < 64 * 16; i += 256) {
    int sl = i >> 4, fi = i & 15;
    float ang = (float)(s0 + sl) * __expf(-(float)fi * 0.575646273248511421f);
    cs0[sl][fi] = cosf(ang);
    sn0[sl][fi] = sinf(ang);
  }
  __syncthreads();
  const size_t row0 = (size_t)(b * S_LEN + s0) * QKV_N;
  const size_t obase = ((size_t)bh * S_LEN + s0) * DPAD;
  for (int i = tid; i < 64 * DPAD; i += 256) {
    int sl = i / DPAD, d = i - sl * DPAD;
    float qv = 0.f, kv = 0.f;
    if (d < HD) {
      const unsigned short* rp = qkv + row0 + (size_t)sl * QKV_N + h * HD;
      float q = bf2f(rp[d]), k = bf2f(rp[HIDDEN + d]);
      if (d < 16) {
        float c = cs0[sl][d], s = sn0[sl][d];
        float q2 = bf2f(rp[d + 16]), k2 = bf2f(rp[HIDDEN + d + 16]);
        qv = q * c - q2 * s;
        kv = k * c - k2 * s;
      } else if (d < 32) {
        float c = cs0[sl][d - 16], s = sn0[sl][d - 16];
        float q1 = bf2f(rp[d - 16]), k1 = bf2f(rp[HIDDEN + d - 16]);
        qv = q * c + q1 * s;
        kv = k * c + k1 * s;
      } else {
        qv = q; kv = k;
      }
    }
    Qw[obase + (size_t)sl * DPAD + d] = f2bf(qv * 0.111803398874989485f); // * 80^-0.5
    Kw[obase + (size_t)sl * DPAD + d] = f2bf(kv);
  }
  for (int i = tid; i < 64 * HD; i += 256) {
    int sl = i / HD, d = i - sl * HD;
    vbuf[sl][d] = qkv[row0 + (size_t)sl * QKV_N + 2 * HIDDEN + h * HD + d];
  }
  __syncthreads();
  const size_t vtb = (size_t)bh * DPAD * S_LEN + s0;
  for (int i = tid; i < DPAD * 64; i += 256) {
    int d = i >> 6, sl = i & 63;
    Vt[vtb + (size_t)d * S_LEN + sl] = (d < HD) ? vbuf[sl][d] : (unsigned short)0;
  }
}

// ---------------- flash attention (causal), QBLK=128, KVBLK=64 ----------------
__global__ __launch_bounds__(256, 2) void k_attn(const unsigned short* __restrict__ Qw,
                                                 const unsigned short* __restrict__ Kw,
                                                 const unsigned short* __restrict__ Vt,
                                                 unsigned short* __restrict__ O) {
  __shared__ unsigned short sK[2][64 * 104];
  __shared__ unsigned short sV[2][80 * 72];
  __shared__ unsigned short sP[4][16 * 72];
  const int p = blockIdx.x;
  const int bh = blockIdx.y;
  const int b = bh >> 5, h = bh & 31;
  const int tid = threadIdx.x;
  const int wave = tid >> 6, lane = tid & 63;
  const int lr = lane >> 4, lc = lane & 15;
  unsigned short* Pw = &sP[wave][0];

  const unsigned short* Kh = Kw + (size_t)bh * S_LEN * DPAD;
  const unsigned short* Vh = Vt + (size_t)bh * DPAD * S_LEN;
  const unsigned short* Qh = Qw + (size_t)bh * S_LEN * DPAD;

  const int kr = tid >> 2, kc = (tid & 3) * 24;
  const int vr = tid >> 3, vc = (tid & 7) * 8;

  u16x8 kst0, kst1, kst2, vst0, vst1, vst2;
  auto gload = [&](int t) {
    const unsigned short* Kg = Kh + ((size_t)(t * 64 + kr)) * DPAD + kc;
    kst0 = *(const u16x8*)(Kg);
    kst1 = *(const u16x8*)(Kg + 8);
    kst2 = *(const u16x8*)(Kg + 16);
    const unsigned short* Vg = Vh + (size_t)vr * S_LEN + t * 64 + vc;
    vst0 = *(const u16x8*)(Vg);
    vst1 = *(const u16x8*)(Vg + 32 * S_LEN);
    if (tid < 128) vst2 = *(const u16x8*)(Vg + (size_t)64 * S_LEN);
  };
  auto swrite = [&](int buf) {
    *(u16x8*)&sK[buf][kr * 104 + kc] = kst0;
    *(u16x8*)&sK[buf][kr * 104 + kc + 8] = kst1;
    *(u16x8*)&sK[buf][kr * 104 + kc + 16] = kst2;
    *(u16x8*)&sV[buf][vr * 72 + vc] = vst0;
    *(u16x8*)&sV[buf][(vr + 32) * 72 + vc] = vst1;
    if (tid < 128) *(u16x8*)&sV[buf][(vr + 64) * 72 + vc] = vst2;
  };

  const f32x4 zero = {0.f, 0.f, 0.f, 0.f};

#pragma unroll 1
  for (int qi = 0; qi < 2; ++qi) {
    const int qt = qi ? (15 - p) : p;
    const int nt = 2 * qt + 2;
    const int wbase = qt * 128 + wave * 32;

    bf16x8 qf[2][3];
#pragma unroll
    for (int m = 0; m < 2; ++m)
#pragma unroll
      for (int ks = 0; ks < 3; ++ks)
        qf[m][ks] = *(const bf16x8*)&Qh[(size_t)(wbase + m * 16 + lc) * DPAD + ks * 32 + lr * 8];

    f32x4 oacc[2][5];
#pragma unroll
    for (int m = 0; m < 2; ++m)
#pragma unroll
      for (int n = 0; n < 5; ++n) oacc[m][n] = zero;
    float mrun[2] = {-1e30f, -1e30f}, lrun[2] = {0.f, 0.f};

    gload(0);
    __syncthreads();
    swrite(0);
    int cur = 0;

#pragma unroll 1
    for (int t = 0; t < nt; ++t) {
      __syncthreads();
      if (t + 1 < nt) gload(t + 1);
      const int ktb = t * 64;
      const bool act0 = ktb <= wbase + 15;
      const bool act1 = ktb <= wbase + 31;
      if (act1) {
        const unsigned short* Kc = sK[cur];
        const unsigned short* Vc = sV[cur];
        f32x4 sf[2][4];
#pragma unroll
        for (int n = 0; n < 4; ++n) {
          sf[0][n] = zero; sf[1][n] = zero;
#pragma unroll
          for (int ks = 0; ks < 3; ++ks) {
            bf16x8 kf = *(const bf16x8*)&Kc[(n * 16 + lc) * 104 + ks * 32 + lr * 8];
            if (act0) sf[0][n] = __builtin_amdgcn_mfma_f32_16x16x32_bf16(kf, qf[0][ks], sf[0][n], 0, 0, 0);
            sf[1][n] = __builtin_amdgcn_mfma_f32_16x16x32_bf16(kf, qf[1][ks], sf[1][n], 0, 0, 0);
          }
        }
        bf16x8 vf[5][2];
#pragma unroll
        for (int n = 0; n < 5; ++n)
#pragma unroll
          for (int ks = 0; ks < 2; ++ks)
            vf[n][ks] = *(const bf16x8*)&Vc[(n * 16 + lc) * 72 + ks * 32 + lr * 8];
#pragma unroll
        for (int m = 0; m < 2; ++m) {
          if (m == 0 && !act0) continue;
          const int qrow0 = wbase + m * 16;
          if (ktb + 63 > qrow0) {
#pragma unroll
            for (int n = 0; n < 4; ++n)
#pragma unroll
              for (int j = 0; j < 4; ++j)
                if (ktb + n * 16 + lr * 4 + j > qrow0 + lc) sf[m][n][j] = -1e30f;
          }
          float t0 = sf[m][0][0];
#pragma unroll
          for (int n = 0; n < 4; ++n)
#pragma unroll
            for (int j = 0; j < 4; ++j) t0 = fmaxf(t0, sf[m][n][j]);
          t0 = fmaxf(t0, __shfl_xor(t0, 16));
          t0 = fmaxf(t0, __shfl_xor(t0, 32));
          const float nm = fmaxf(mrun[m], t0);
          const float corrq = __expf(mrun[m] - nm);
          mrun[m] = nm;
          float ps = 0.f;
#pragma unroll
          for (int n = 0; n < 4; ++n)
#pragma unroll
            for (int j = 0; j < 4; ++j) {
              float e = __expf(sf[m][n][j] - nm);
              sf[m][n][j] = e;
              ps += e;
            }
          ps += __shfl_xor(ps, 16);
          ps += __shfl_xor(ps, 32);
          lrun[m] = lrun[m] * corrq + ps;
          float cj[4];
#pragma unroll
          for (int j = 0; j < 4; ++j) cj[j] = __shfl(corrq, lr * 4 + j, 16);
#pragma unroll
          for (int n = 0; n < 5; ++n)
#pragma unroll
            for (int j = 0; j < 4; ++j) oacc[m][n][j] *= cj[j];
#pragma unroll
          for (int n = 0; n < 4; ++n) {
            unsigned lo = (unsigned)f2bf(sf[m][n][0]) | ((unsigned)f2bf(sf[m][n][1]) << 16);
            unsigned hi = (unsigned)f2bf(sf[m][n][2]) | ((unsigned)f2bf(sf[m][n][3]) << 16);
            uint2 u; u.x = lo; u.y = hi;
            *(uint2*)&Pw[lc * 72 + n * 16 + lr * 4] = u;
          }
          asm volatile("" ::: "memory");
          bf16x8 pa0 = *(const bf16x8*)&Pw[lc * 72 + lr * 8];
          bf16x8 pa1 = *(const bf16x8*)&Pw[lc * 72 + 32 + lr * 8];
#pragma unroll
          for (int n = 0; n < 5; ++n) {
            oacc[m][n] = __builtin_amdgcn_mfma_f32_16x16x32_bf16(pa0, vf[n][0], oacc[m][n], 0, 0, 0);
            oacc[m][n] = __builtin_amdgcn_mfma_f32_16x16x32_bf16(pa1, vf[n][1], oacc[m][n], 0, 0, 0);
          }
          asm volatile("" ::: "memory");
        }
      }
      if (t + 1 < nt) swrite(cur ^ 1);
      cur ^= 1;
    }

#pragma unroll
    for (int m = 0; m < 2; ++m) {
      float linv[4];
#pragma unroll
      for (int j = 0; j < 4; ++j) {
        float lj = __shfl(lrun[m], lr * 4 + j, 16);
        linv[j] = 1.f / lj;
      }
      const int q0 = wbase + m * 16 + lr * 4;
#pragma unroll
      for (int n = 0; n < 5; ++n) {
        const int d = n * 16 + lc;
#pragma unroll
        for (int j = 0; j < 4; ++j)
          O[((size_t)(b * S_LEN) + q0 + j) * HIDDEN + h * HD + d] = f2bf(oacc[m][n][j] * linv[j]);
      }
    }
  }
}

extern "C" void kernel_launch(void* const* d_in, const int* in_sizes, int n_in,
                              void* d_out, int out_size, void* d_ws, size_t ws_size,
                              hipStream_t stream) {
  (void)in_sizes; (void)n_in; (void)out_size; (void)ws_size;
  const float* hidden  = (const float*)d_in[1];
  const float* w_qkv   = (const float*)d_in[2];
  const float* b_qkv   = (const float*)d_in[3];
  const float* w_dense = (const float*)d_in[4];
  const float* b_dense = (const float*)d_in[5];
  char* ws = (char*)d_ws;
  unsigned short* Abf   = (unsigned short*)(ws + 0);          // 4096x2560 bf16
  unsigned short* Wqkvt = (unsigned short*)(ws + 20971520);   // 7680x2560 bf16
  unsigned short* Wdt   = (unsigned short*)(ws + 60293120);   // 2560x2560 bf16
  unsigned short* QKVb  = (unsigned short*)(ws + 73400320);   // 4096x7680 bf16
  unsigned short* Qw    = (unsigned short*)(ws + 136314880);  // 64x2048x96 bf16
  unsigned short* Kw    = (unsigned short*)(ws + 161480704);
  unsigned short* Vt    = (unsigned short*)(ws + 186646528);
  unsigned short* Obf   = (unsigned short*)(ws + 211812352);  // 4096x2560 bf16

  k_cvt<<<10240, 256, 0, stream>>>(hidden, Abf, 2621440);
  k_transpose_bf16<<<dim3(120, 40), 256, 0, stream>>>(w_qkv, Wqkvt, 2560, 7680);
  k_transpose_bf16<<<dim3(40, 40), 256, 0, stream>>>(w_dense, Wdt, 2560, 2560);
  k_gemm1<<<480, 512, 0, stream>>>(Abf, Wqkvt, b_qkv, QKVb, 4096, 7680, 2560);
  k_rope<<<2048, 256, 0, stream>>>(QKVb, Qw, Kw, Vt);
  k_attn<<<dim3(8, 64), 256, 0, stream>>>(Qw, Kw, Vt, Obf);
  k_gemm_t<128><<<640, 256, 0, stream>>>(Obf, Wdt, b_dense, nullptr, (float*)d_out, 4096, 2560, 2560, 1);
}